// Round 8
// baseline (115.888 us; speedup 1.0000x reference)
//
#include <hip/hip_runtime.h>

// B=8, C=128, H=W=64 -> N=4096 tokens/batch. d_qk=32.
// R8: R6 attn core (single-quarter K staging) + setprio(PV) + R7 packed
// raw-layout partial-O epilogue/out_kernel + lnqkv V-write via LDS staging.
// Split-K(4) gated on ws_size (fallback 2).

#define NB 8
#define CCH 128
#define NTOK 4096
#define DQK 32
#define KT 64
#define PARTSZ 4194304   // u16 per partial-O part (32768*128)

typedef __attribute__((ext_vector_type(8))) short bf16x8;
typedef __attribute__((ext_vector_type(4))) float f32x4;
typedef unsigned short u16;
typedef unsigned int u32;

static __device__ __forceinline__ f32x4 mfma16(bf16x8 a, bf16x8 b, f32x4 c) {
  return __builtin_amdgcn_mfma_f32_16x16x32_bf16(a, b, c, 0, 0, 0);
}
static __device__ __forceinline__ u16 f2bf(float f) {
  union { float f; u32 u; } cv; cv.f = f;
  u32 u = cv.u;
  u += 0x7fffu + ((u >> 16) & 1u);
  return (u16)(u >> 16);
}
static __device__ __forceinline__ float bf2f(u16 v) {
  union { u32 u; float f; } cv; cv.u = ((u32)v) << 16;
  return cv.f;
}
static __device__ __forceinline__ u32 cvtpk(float lo, float hi) {
  u32 d;
  asm("v_cvt_pk_bf16_f32 %0, %1, %2" : "=v"(d) : "v"(lo), "v"(hi));
  return d;
}
static __device__ __forceinline__ void gload16(const void* g, void* l) {
  __builtin_amdgcn_global_load_lds(
      (const __attribute__((address_space(1))) void*)g,
      (__attribute__((address_space(3))) void*)l, 16, 0, 0);
}

// ---------------- kernel 0: weights -> bf16 [320][128] ----------------------
__global__ __launch_bounds__(256) void wconv_kernel(
    const float* __restrict__ Wq, const float* __restrict__ Wk,
    const float* __restrict__ Wv, const float* __restrict__ Wo,
    u16* __restrict__ wcomb) {
  int idx = blockIdx.x * 256 + threadIdx.x;
  int r = idx >> 7;
  float v;
  if (r < 32)        v = Wq[idx];
  else if (r < 64)   v = Wk[idx - 4096];
  else if (r < 192)  v = Wv[idx - 8192];
  else               v = Wo[idx - 24576];
  wcomb[idx] = f2bf(v);
}

// ---------------- kernel 1: fused LayerNorm + QKV projection ----------------
// V is staged permuted into LDS (overlay of dead `tile`), then copied out as
// contiguous 128B rows per channel (coalesced), replacing scattered 2B stores.
__global__ __launch_bounds__(256) void lnqkv_kernel(
    const float* __restrict__ x, const float* __restrict__ gamma,
    const float* __restrict__ beta, const u16* __restrict__ wcomb,
    u16* __restrict__ Qg, u16* __restrict__ Kg, u16* __restrict__ Vt) {
  __shared__ float tile[128][64];   // reused as vl[128][72] u16 after GEMM reads
  __shared__ float red[2][4][64];
  __shared__ u16   xt[64][130];
  int t = threadIdx.x;
  int lane = t & 63, cq = t >> 6;
  int b = blockIdx.x >> 6;
  int posb = (blockIdx.x & 63) << 6;
  const float* xb = x + ((size_t)b * CCH) * NTOK + posb;
  for (int i = 0; i < 32; ++i) {
    int c = cq * 32 + i;
    tile[c][lane] = xb[(size_t)c * NTOK + lane];
  }
  __syncthreads();
  float s = 0.f, s2 = 0.f;
  for (int i = 0; i < 32; ++i) {
    float v = tile[cq * 32 + i][lane];
    s += v; s2 += v * v;
  }
  red[0][cq][lane] = s; red[1][cq][lane] = s2;
  __syncthreads();
  float mu  = (red[0][0][lane] + red[0][1][lane] + red[0][2][lane] + red[0][3][lane]) * (1.f / 128.f);
  float ex2 = (red[1][0][lane] + red[1][1][lane] + red[1][2][lane] + red[1][3][lane]) * (1.f / 128.f);
  float rstd = rsqrtf(ex2 - mu * mu + 1e-5f);
  for (int i = 0; i < 32; ++i) {
    int c = cq * 32 + i;
    float v = (tile[c][lane] - mu) * rstd * gamma[c] + beta[c];
    xt[lane][c] = f2bf(v);
  }
  __syncthreads();   // after this, `tile` is dead -> overlay vl
  u16* vl = (u16*)tile;            // [128][72] u16, 18 KB
  int w = t >> 6, row16 = lane & 15, kgrp = lane >> 4;
  bf16x8 af[4];
  for (int ks = 0; ks < 4; ++ks)
    af[ks] = *(const bf16x8*)&xt[w * 16 + row16][ks * 32 + kgrp * 8];
  f32x4 zero = {0.f, 0.f, 0.f, 0.f};
  f32x4 acc[12];
  for (int nt = 0; nt < 12; ++nt) {
    acc[nt] = zero;
    for (int ks = 0; ks < 4; ++ks) {
      bf16x8 bf = *(const bf16x8*)&wcomb[(size_t)(nt * 16 + row16) * CCH + ks * 32 + kgrp * 8];
      acc[nt] = mfma16(af[ks], bf, acc[nt]);
    }
  }
  int tok0 = b * NTOK + posb;
  for (int nt = 0; nt < 12; ++nt) {
    int col = nt * 16 + row16;
    for (int r = 0; r < 4; ++r) {
      int token = tok0 + w * 16 + kgrp * 4 + r;
      if (col < 32) {
        Qg[(size_t)token * DQK + col] = f2bf(acc[nt][r] * 1.44269504f);
      } else if (col < 64) {
        Kg[(size_t)token * DQK + (col - 32)] = f2bf(acc[nt][r]);
      } else {
        int j = w * 16 + kgrp * 4 + r;   // local token 0..63
        int kpl = (j & 32) | ((j & 12) << 1) | ((j & 16) >> 2) | (j & 3);
        vl[(col - 64) * 72 + kpl] = f2bf(acc[nt][r]);
      }
    }
  }
  __syncthreads();
  // copy-out V: 2 threads per channel row, 64B each, fully-utilized 128B lines
  int c = t >> 1, hh = (t & 1) * 32;
  u16* dst = Vt + ((size_t)b * CCH + c) * NTOK + posb + hh;
  const u16* srcv = &vl[c * 72 + hh];
#pragma unroll
  for (int i = 0; i < 4; ++i)
    *(uint4*)&dst[i * 8] = *(const uint4*)&srcv[i * 8];
}

// ---------------- kernel 2: flash attention ---------------------------------
// 4 waves x 32q = 128 q/block; split-K(NS); grid 256*NS.
// K LDS (4KB/tile): key-pair rows, slot phys=(k>>1)*8+(((k&1)*4+f)^((k>>1)&7));
//   each wave stages ONE quarter (1 gload16/wave).
// V LDS (16KB/tile): [c][8 slots of 16B], phys = c*64u16 + (s^(c&7))*8.
// l via ones-column MFMA. Partial O in packed raw lane layout (R7).
template <int NS>
__global__ __launch_bounds__(256, 4) void attn_kernel(
    const u16* __restrict__ Qg, const u16* __restrict__ Kg,
    const u16* __restrict__ Vt, u16* __restrict__ Op,
    float* __restrict__ lp) {
  __shared__ u16 lds[2][10240];   // per buf: K 2048 u16 (4KB) + V 8192 u16 (16KB)
  constexpr int KSEG = NTOK / NS;
  constexpr int NTILE = KSEG / KT;
  constexpr int BSH = (NS == 4) ? 7 : 6;
  int t = threadIdx.x;
  int w = t >> 6, lane = t & 63;
  int row16 = lane & 15, kgrp = lane >> 4;

  int cpx = (256 * NS) >> 3;
  int logical = (blockIdx.x & 7) * cpx + (blockIdx.x >> 3);  // XCD-chunked
  int qblk = logical & 31;
  int part = (logical >> 5) & (NS - 1);
  int b = logical >> BSH;
  int q0 = qblk * 128;
  int kt0 = part * KSEG;

  const u16* Qb = Qg + ((size_t)(b * NTOK + q0 + w * 32)) * DQK;
  bf16x8 qf0 = *(const bf16x8*)&Qb[(size_t)row16 * DQK + kgrp * 8];
  bf16x8 qf1 = *(const bf16x8*)&Qb[(size_t)(16 + row16) * DQK + kgrp * 8];

  bf16x8 ones_b;
  {
    short val = (row16 == 0) ? (short)0x3F80 : (short)0;
    for (int j = 0; j < 8; ++j) ones_b[j] = val;
  }

  // per-thread staging sources (inverse-XOR-swizzled globals) — R6 form
  int pr = t >> 3, e8 = t & 7;
  int korig = e8 ^ (pr & 7);
  int kkey = pr * 2 + (korig >> 2);
  int kfs = korig & 3;
  const u16* ksrc = Kg + (size_t)(b * NTOK + kt0 + kkey) * DQK + kfs * 8;
  int cV = t >> 3;
  int sV = e8 ^ (cV & 7);
  const u16* vsrc = Vt + ((size_t)b * CCH + cV) * NTOK + kt0 + sV * 8;

  int kdst = w * 512;
  int vdst = w * 512;

  f32x4 zero = {0.f, 0.f, 0.f, 0.f};
  f32x4 o0[8], o1[8], ol0, ol1;
#pragma unroll
  for (int i = 0; i < 8; ++i) { o0[i] = zero; o1[i] = zero; }
  ol0 = zero; ol1 = zero;

  auto stage = [&](int bi, int tile) {
    const u16* kp_ = ksrc + (size_t)tile * (KT * DQK);
    gload16(kp_, &lds[bi][kdst]);
    const u16* vp_ = vsrc + tile * KT;
    gload16(vp_,          &lds[bi][2048 + vdst]);
    gload16(vp_ + 131072, &lds[bi][2048 + 2048 + vdst]);
    gload16(vp_ + 262144, &lds[bi][2048 + 4096 + vdst]);
    gload16(vp_ + 393216, &lds[bi][2048 + 6144 + vdst]);
  };

  auto compute = [&](int bi) {
    const u16* kb = &lds[bi][0];
    const u16* vb = &lds[bi][2048];
    f32x4 sa0[4], sa1[4];
#pragma unroll
    for (int nt = 0; nt < 4; ++nt) {
      int slot = (nt * 8 + (row16 >> 1)) * 8 +
                 ((((row16 & 1) << 2) + kgrp) ^ (row16 >> 1));
      bf16x8 kf = *(const bf16x8*)&kb[slot * 8];
      sa0[nt] = mfma16(kf, qf0, zero);
      sa1[nt] = mfma16(kf, qf1, zero);
    }
#pragma unroll
    for (int nt = 0; nt < 4; ++nt)
      for (int r = 0; r < 4; ++r) {
        sa0[nt][r] = __builtin_amdgcn_exp2f(sa0[nt][r]);
        sa1[nt][r] = __builtin_amdgcn_exp2f(sa1[nt][r]);
      }
    union PU { u32 d[4]; bf16x8 v; };
    PU pf0[2], pf1[2];
#pragma unroll
    for (int ks = 0; ks < 2; ++ks) {
      pf0[ks].d[0] = cvtpk(sa0[2 * ks][0], sa0[2 * ks][1]);
      pf0[ks].d[1] = cvtpk(sa0[2 * ks][2], sa0[2 * ks][3]);
      pf0[ks].d[2] = cvtpk(sa0[2 * ks + 1][0], sa0[2 * ks + 1][1]);
      pf0[ks].d[3] = cvtpk(sa0[2 * ks + 1][2], sa0[2 * ks + 1][3]);
      pf1[ks].d[0] = cvtpk(sa1[2 * ks][0], sa1[2 * ks][1]);
      pf1[ks].d[1] = cvtpk(sa1[2 * ks][2], sa1[2 * ks][3]);
      pf1[ks].d[2] = cvtpk(sa1[2 * ks + 1][0], sa1[2 * ks + 1][1]);
      pf1[ks].d[3] = cvtpk(sa1[2 * ks + 1][2], sa1[2 * ks + 1][3]);
    }
    __builtin_amdgcn_s_setprio(1);
    ol0 = mfma16(pf0[0].v, ones_b, ol0);
    ol0 = mfma16(pf0[1].v, ones_b, ol0);
    ol1 = mfma16(pf1[0].v, ones_b, ol1);
    ol1 = mfma16(pf1[1].v, ones_b, ol1);
#pragma unroll
    for (int ks = 0; ks < 2; ++ks)
#pragma unroll
      for (int ntc = 0; ntc < 8; ++ntc) {
        int vslot = (ntc * 16 + row16) * 8 + (((ks << 2) + kgrp) ^ (row16 & 7));
        bf16x8 vf = *(const bf16x8*)&vb[vslot * 8];
        o0[ntc] = mfma16(pf0[ks].v, vf, o0[ntc]);
        o1[ntc] = mfma16(pf1[ks].v, vf, o1[ntc]);
      }
    __builtin_amdgcn_s_setprio(0);
  };

  stage(0, 0);
  asm volatile("s_waitcnt vmcnt(0)" ::: "memory");
  __builtin_amdgcn_s_barrier();
  int cur = 0;
  for (int tile = 0; tile < NTILE - 1; ++tile) {
    stage(cur ^ 1, tile + 1);
    compute(cur);
    asm volatile("s_waitcnt vmcnt(0)" ::: "memory");
    __builtin_amdgcn_s_barrier();
    cur ^= 1;
  }
  compute(cur);

  // epilogue: packed raw-layout partial O (8 coalesced 16B stores/lane)
  u32 word[32];
#pragma unroll
  for (int sub = 0; sub < 2; ++sub) {
#pragma unroll
    for (int ntc = 0; ntc < 8; ++ntc) {
      f32x4 ov = sub ? o1[ntc] : o0[ntc];
      word[sub * 16 + ntc * 2]     = cvtpk(ov[0], ov[1]);
      word[sub * 16 + ntc * 2 + 1] = cvtpk(ov[2], ov[3]);
    }
  }
  u16* Opw = Op + (size_t)part * PARTSZ;
  size_t blkb = ((size_t)(b * NTOK + q0)) * CCH;
#pragma unroll
  for (int j = 0; j < 8; ++j) {
    uint4 v4;
    v4.x = word[4 * j]; v4.y = word[4 * j + 1];
    v4.z = word[4 * j + 2]; v4.w = word[4 * j + 3];
    *(uint4*)&Opw[blkb + w * 4096 + j * 512 + lane * 8] = v4;
  }
  int tokb = b * NTOK + q0 + w * 32;
  if (row16 == 0) {
#pragma unroll
    for (int r = 0; r < 4; ++r) {
      lp[part * 32768 + tokb + kgrp * 4 + r] = ol0[r];
      lp[part * 32768 + tokb + 16 + kgrp * 4 + r] = ol1[r];
    }
  }
}

// ---------------- kernel 3: combine parts + Wo GEMM + bias + residual -------
// 256 blocks x 128 tokens, thread mapping mirrors attn's raw layout.
__global__ __launch_bounds__(256) void out_kernel(
    const u16* __restrict__ Op, const float* __restrict__ lp, int ns,
    const u16* __restrict__ wcomb, const float* __restrict__ bo,
    const float* __restrict__ x, float* __restrict__ out) {
  __shared__ float lred[128];
  __shared__ u16 xt[128][132];
  int t = threadIdx.x;
  int w = t >> 6, lane = t & 63;
  int row16 = lane & 15, kgrp = lane >> 4;
  int blk = blockIdx.x;
  int tok0 = blk * 128;
  int b = tok0 >> 12, tloc = tok0 & (NTOK - 1);

  if (t < 128) {
    float s = 0.f;
    for (int p = 0; p < ns; ++p) s += lp[p * 32768 + tok0 + t];
    lred[t] = 1.f / s;
  }
  __syncthreads();
  float linv[2][4];
#pragma unroll
  for (int sub = 0; sub < 2; ++sub)
#pragma unroll
    for (int r = 0; r < 4; ++r)
      linv[sub][r] = lred[w * 32 + sub * 16 + kgrp * 4 + r];

  size_t blkb = (size_t)tok0 * CCH;
#pragma unroll
  for (int j = 0; j < 8; ++j) {
    float s[8] = {0.f, 0.f, 0.f, 0.f, 0.f, 0.f, 0.f, 0.f};
    for (int p = 0; p < ns; ++p) {
      uint4 v4 = *(const uint4*)&Op[(size_t)p * PARTSZ + blkb + w * 4096 + j * 512 + lane * 8];
      u32 ww[4] = {v4.x, v4.y, v4.z, v4.w};
#pragma unroll
      for (int m = 0; m < 4; ++m) {
        s[2 * m]     += bf2f((u16)(ww[m] & 0xffffu));
        s[2 * m + 1] += bf2f((u16)(ww[m] >> 16));
      }
    }
    int sub = j >> 2;
#pragma unroll
    for (int m = 0; m < 4; ++m) {
      int i = 4 * j + m;
      int ntc = (i >> 1) & 7, pr = i & 1;
      int c = ntc * 16 + row16;
#pragma unroll
      for (int dd = 0; dd < 2; ++dd) {
        int r = 2 * pr + dd;
        xt[w * 32 + sub * 16 + kgrp * 4 + r][c] = f2bf(s[2 * m + dd] * linv[sub][r]);
      }
    }
  }
  __syncthreads();

  f32x4 zero = {0.f, 0.f, 0.f, 0.f};
  f32x4 acc[2][8];
#pragma unroll
  for (int sub = 0; sub < 2; ++sub)
    for (int nt = 0; nt < 8; ++nt) acc[sub][nt] = zero;
#pragma unroll
  for (int ks = 0; ks < 4; ++ks) {
    bf16x8 af0 = *(const bf16x8*)&xt[w * 32 + row16][ks * 32 + kgrp * 8];
    bf16x8 af1 = *(const bf16x8*)&xt[w * 32 + 16 + row16][ks * 32 + kgrp * 8];
#pragma unroll
    for (int nt = 0; nt < 8; ++nt) {
      bf16x8 bfv = *(const bf16x8*)&wcomb[(size_t)(192 + nt * 16 + row16) * CCH + ks * 32 + kgrp * 8];
      acc[0][nt] = mfma16(af0, bfv, acc[0][nt]);
      acc[1][nt] = mfma16(af1, bfv, acc[1][nt]);
    }
  }
#pragma unroll
  for (int sub = 0; sub < 2; ++sub)
#pragma unroll
    for (int nt = 0; nt < 8; ++nt) {
      int cout = nt * 16 + row16;
      float bias = bo[cout];
      size_t base = ((size_t)b * CCH + cout) * NTOK + tloc + w * 32 + sub * 16 + kgrp * 4;
      float4 xr = *(const float4*)&x[base];
      float4 ov;
      ov.x = acc[sub][nt][0] + bias + xr.x;
      ov.y = acc[sub][nt][1] + bias + xr.y;
      ov.z = acc[sub][nt][2] + bias + xr.z;
      ov.w = acc[sub][nt][3] + bias + xr.w;
      *(float4*)&out[base] = ov;
    }
}

extern "C" void kernel_launch(void* const* d_in, const int* in_sizes, int n_in,
                              void* d_out, int out_size, void* d_ws, size_t ws_size,
                              hipStream_t stream) {
  const float* x     = (const float*)d_in[0];
  const float* gamma = (const float*)d_in[1];
  const float* beta  = (const float*)d_in[2];
  const float* Wq    = (const float*)d_in[3];
  const float* Wk    = (const float*)d_in[4];
  const float* Wv    = (const float*)d_in[5];
  const float* Wo    = (const float*)d_in[6];
  const float* bo    = (const float*)d_in[7];
  float* out = (float*)d_out;

  unsigned char* ws = (unsigned char*)d_ws;
  u16* Qg    = (u16*)(ws);                  //  2 MB
  u16* Kg    = (u16*)(ws + 2097152);        //  2 MB
  u16* Vt    = (u16*)(ws + 4194304);        //  8 MB [8][128][4096] key-permuted
  u16* wcomb = (u16*)(ws + 12582912);       //  80 KB
  float* lp  = (float*)(ws + 12664832);     //  ns*128 KB
  u16* Op    = (u16*)(ws + 13189120);       //  ns*8 MB raw-layout partials

  int ns = (ws_size >= 46743552u) ? 4 : 2;

  wconv_kernel<<<160, 256, 0, stream>>>(Wq, Wk, Wv, Wo, wcomb);
  lnqkv_kernel<<<512, 256, 0, stream>>>(x, gamma, beta, wcomb, Qg, Kg, Vt);
  if (ns == 4)
    attn_kernel<4><<<1024, 256, 0, stream>>>(Qg, Kg, Vt, Op, lp);
  else
    attn_kernel<2><<<512, 256, 0, stream>>>(Qg, Kg, Vt, Op, lp);
  out_kernel<<<256, 256, 0, stream>>>(Op, lp, ns, wcomb, bo, x, out);
}

// Round 11
// 93.511 us; speedup vs baseline: 1.2393x; 1.2393x over previous
//
#include <hip/hip_runtime.h>

// B=8, C=128, H=W=64 -> N=4096 tokens/batch. d_qk=32.
// R11 = EXACT resubmit of the Round-6 kernel (last known-good, 93.2 us) to
// re-anchor after two unexplained NaN rounds. 32q/wave (2 q-subtiles),
// split-K(4) gated on ws_size (fallback split-2), l via ones-column MFMA.
// Swapped QK^T + key-permuted V (P in-lane), XOR-swizzled LDS via
// pre-swizzled global_load_lds, 2-phase dbuf. Fused LN+QKV.

#define NB 8
#define CCH 128
#define NTOK 4096
#define DQK 32
#define KT 64

typedef __attribute__((ext_vector_type(8))) short bf16x8;
typedef __attribute__((ext_vector_type(4))) float f32x4;
typedef unsigned short u16;
typedef unsigned int u32;

static __device__ __forceinline__ f32x4 mfma16(bf16x8 a, bf16x8 b, f32x4 c) {
  return __builtin_amdgcn_mfma_f32_16x16x32_bf16(a, b, c, 0, 0, 0);
}
static __device__ __forceinline__ u16 f2bf(float f) {
  union { float f; u32 u; } cv; cv.f = f;
  u32 u = cv.u;
  u += 0x7fffu + ((u >> 16) & 1u);
  return (u16)(u >> 16);
}
static __device__ __forceinline__ float bf2f(u16 v) {
  union { u32 u; float f; } cv; cv.u = ((u32)v) << 16;
  return cv.f;
}
static __device__ __forceinline__ u32 cvtpk(float lo, float hi) {
  u32 d;
  asm("v_cvt_pk_bf16_f32 %0, %1, %2" : "=v"(d) : "v"(lo), "v"(hi));
  return d;
}
static __device__ __forceinline__ void gload16(const void* g, void* l) {
  __builtin_amdgcn_global_load_lds(
      (const __attribute__((address_space(1))) void*)g,
      (__attribute__((address_space(3))) void*)l, 16, 0, 0);
}

// ---------------- kernel 0: weights -> bf16 [320][128] ----------------------
__global__ __launch_bounds__(256) void wconv_kernel(
    const float* __restrict__ Wq, const float* __restrict__ Wk,
    const float* __restrict__ Wv, const float* __restrict__ Wo,
    u16* __restrict__ wcomb) {
  int idx = blockIdx.x * 256 + threadIdx.x;
  int r = idx >> 7;
  float v;
  if (r < 32)        v = Wq[idx];
  else if (r < 64)   v = Wk[idx - 4096];
  else if (r < 192)  v = Wv[idx - 8192];
  else               v = Wo[idx - 24576];
  wcomb[idx] = f2bf(v);
}

// ---------------- kernel 1: fused LayerNorm + QKV projection ----------------
__global__ __launch_bounds__(256) void lnqkv_kernel(
    const float* __restrict__ x, const float* __restrict__ gamma,
    const float* __restrict__ beta, const u16* __restrict__ wcomb,
    u16* __restrict__ Qg, u16* __restrict__ Kg, u16* __restrict__ Vt) {
  __shared__ float tile[128][64];
  __shared__ float red[2][4][64];
  __shared__ u16   xt[64][130];
  int t = threadIdx.x;
  int lane = t & 63, cq = t >> 6;
  int b = blockIdx.x >> 6;
  int posb = (blockIdx.x & 63) << 6;
  const float* xb = x + ((size_t)b * CCH) * NTOK + posb;
  for (int i = 0; i < 32; ++i) {
    int c = cq * 32 + i;
    tile[c][lane] = xb[(size_t)c * NTOK + lane];
  }
  __syncthreads();
  float s = 0.f, s2 = 0.f;
  for (int i = 0; i < 32; ++i) {
    float v = tile[cq * 32 + i][lane];
    s += v; s2 += v * v;
  }
  red[0][cq][lane] = s; red[1][cq][lane] = s2;
  __syncthreads();
  float mu  = (red[0][0][lane] + red[0][1][lane] + red[0][2][lane] + red[0][3][lane]) * (1.f / 128.f);
  float ex2 = (red[1][0][lane] + red[1][1][lane] + red[1][2][lane] + red[1][3][lane]) * (1.f / 128.f);
  float rstd = rsqrtf(ex2 - mu * mu + 1e-5f);
  for (int i = 0; i < 32; ++i) {
    int c = cq * 32 + i;
    float v = (tile[c][lane] - mu) * rstd * gamma[c] + beta[c];
    xt[lane][c] = f2bf(v);
  }
  __syncthreads();
  int w = t >> 6, row16 = lane & 15, kgrp = lane >> 4;
  bf16x8 af[4];
  for (int ks = 0; ks < 4; ++ks)
    af[ks] = *(const bf16x8*)&xt[w * 16 + row16][ks * 32 + kgrp * 8];
  f32x4 zero = {0.f, 0.f, 0.f, 0.f};
  f32x4 acc[12];
  for (int nt = 0; nt < 12; ++nt) {
    acc[nt] = zero;
    for (int ks = 0; ks < 4; ++ks) {
      bf16x8 bf = *(const bf16x8*)&wcomb[(size_t)(nt * 16 + row16) * CCH + ks * 32 + kgrp * 8];
      acc[nt] = mfma16(af[ks], bf, acc[nt]);
    }
  }
  int tok0 = b * NTOK + posb;
  for (int nt = 0; nt < 12; ++nt) {
    int col = nt * 16 + row16;
    for (int r = 0; r < 4; ++r) {
      int token = tok0 + w * 16 + kgrp * 4 + r;
      if (col < 32) {
        Qg[(size_t)token * DQK + col] = f2bf(acc[nt][r] * 1.44269504f);
      } else if (col < 64) {
        Kg[(size_t)token * DQK + (col - 32)] = f2bf(acc[nt][r]);
      } else {
        int tl = token & (NTOK - 1);
        int kp = (tl & ~31) | ((tl & 12) << 1) | ((tl & 16) >> 2) | (tl & 3);
        Vt[((size_t)b * CCH + (col - 64)) * NTOK + kp] = f2bf(acc[nt][r]);
      }
    }
  }
}

// ---------------- kernel 2: flash attention ---------------------------------
// 4 waves x 32q = 128 q/block; split-K(NS); grid 256*NS.
// K LDS: key-pair rows (128B), slot phys=(k>>1)*8 + (((k&1)*4+f)^((k>>1)&7))
// V LDS: [c][8 slots of 16B], phys = c*64u16 + (s^(c&7))*8; V pre-permuted.
// l via ones-column MFMA: ol = P * [1,0,...,0]^T accumulated in f32.
template <int NS>
__global__ __launch_bounds__(256, 4) void attn_kernel(
    const u16* __restrict__ Qg, const u16* __restrict__ Kg,
    const u16* __restrict__ Vt, u16* __restrict__ Op,
    float* __restrict__ lp) {
  __shared__ u16 lds[2][10240];   // per buf: K 2048 u16 (4KB) + V 8192 u16 (16KB)
  constexpr int KSEG = NTOK / NS;         // keys per split segment
  constexpr int NTILE = KSEG / KT;        // tiles per block
  constexpr int BSH = (NS == 4) ? 7 : 6;  // qblk(5) + part bits
  int t = threadIdx.x;
  int w = t >> 6, lane = t & 63;
  int row16 = lane & 15, kgrp = lane >> 4;

  int cpx = (256 * NS) >> 3;
  int logical = (blockIdx.x & 7) * cpx + (blockIdx.x >> 3);  // XCD-chunked
  int qblk = logical & 31;
  int part = (logical >> 5) & (NS - 1);
  int b = logical >> BSH;
  int q0 = qblk * 128;
  int kt0 = part * KSEG;

  // Q fragments (B-operand of swapped QK^T): 2 q-subtiles of 16
  const u16* Qb = Qg + ((size_t)(b * NTOK + q0 + w * 32)) * DQK;
  bf16x8 qf0 = *(const bf16x8*)&Qb[(size_t)row16 * DQK + kgrp * 8];
  bf16x8 qf1 = *(const bf16x8*)&Qb[(size_t)(16 + row16) * DQK + kgrp * 8];

  // ones B-fragment: B[k][col] = (col==0) ? 1 : 0  (col = row16)
  bf16x8 ones_b;
  {
    short one = (short)0x3F80;
    short val = (row16 == 0) ? one : (short)0;
    for (int j = 0; j < 8; ++j) ones_b[j] = val;
  }

  // per-thread staging sources (inverse-XOR-swizzled globals)
  int pr = t >> 3, e8 = t & 7;
  int korig = e8 ^ (pr & 7);
  int kkey = pr * 2 + (korig >> 2);
  int kfs = korig & 3;
  const u16* ksrc = Kg + (size_t)(b * NTOK + kt0 + kkey) * DQK + kfs * 8;
  int cV = t >> 3;
  int sV = e8 ^ (cV & 7);
  const u16* vsrc = Vt + ((size_t)b * CCH + cV) * NTOK + kt0 + sV * 8;

  int kdst = w * 512;
  int vdst = w * 512;

  f32x4 zero = {0.f, 0.f, 0.f, 0.f};
  f32x4 o0[8], o1[8], ol0, ol1;
#pragma unroll
  for (int i = 0; i < 8; ++i) { o0[i] = zero; o1[i] = zero; }
  ol0 = zero; ol1 = zero;

  auto stage = [&](int bi, int tile) {
    const u16* kp_ = ksrc + (size_t)tile * (KT * DQK);
    gload16(kp_, &lds[bi][kdst]);
    const u16* vp_ = vsrc + tile * KT;
    gload16(vp_,          &lds[bi][2048 + vdst]);
    gload16(vp_ + 131072, &lds[bi][2048 + 2048 + vdst]);
    gload16(vp_ + 262144, &lds[bi][2048 + 4096 + vdst]);
    gload16(vp_ + 393216, &lds[bi][2048 + 6144 + vdst]);
  };

  auto compute = [&](int bi) {
    const u16* kb = &lds[bi][0];
    const u16* vb = &lds[bi][2048];
    f32x4 sa0[4], sa1[4];
#pragma unroll
    for (int nt = 0; nt < 4; ++nt) {
      int slot = (nt * 8 + (row16 >> 1)) * 8 +
                 ((((row16 & 1) << 2) + kgrp) ^ (row16 >> 1));
      bf16x8 kf = *(const bf16x8*)&kb[slot * 8];
      sa0[nt] = mfma16(kf, qf0, zero);
      sa1[nt] = mfma16(kf, qf1, zero);
    }
#pragma unroll
    for (int nt = 0; nt < 4; ++nt)
      for (int r = 0; r < 4; ++r) {
        sa0[nt][r] = __builtin_amdgcn_exp2f(sa0[nt][r]);
        sa1[nt][r] = __builtin_amdgcn_exp2f(sa1[nt][r]);
      }
    union PU { u32 d[4]; bf16x8 v; };
    PU pf0[2], pf1[2];
#pragma unroll
    for (int ks = 0; ks < 2; ++ks) {
      pf0[ks].d[0] = cvtpk(sa0[2 * ks][0], sa0[2 * ks][1]);
      pf0[ks].d[1] = cvtpk(sa0[2 * ks][2], sa0[2 * ks][3]);
      pf0[ks].d[2] = cvtpk(sa0[2 * ks + 1][0], sa0[2 * ks + 1][1]);
      pf0[ks].d[3] = cvtpk(sa0[2 * ks + 1][2], sa0[2 * ks + 1][3]);
      pf1[ks].d[0] = cvtpk(sa1[2 * ks][0], sa1[2 * ks][1]);
      pf1[ks].d[1] = cvtpk(sa1[2 * ks][2], sa1[2 * ks][3]);
      pf1[ks].d[2] = cvtpk(sa1[2 * ks + 1][0], sa1[2 * ks + 1][1]);
      pf1[ks].d[3] = cvtpk(sa1[2 * ks + 1][2], sa1[2 * ks + 1][3]);
    }
    // l accumulation on the MFMA pipe
    ol0 = mfma16(pf0[0].v, ones_b, ol0);
    ol0 = mfma16(pf0[1].v, ones_b, ol0);
    ol1 = mfma16(pf1[0].v, ones_b, ol1);
    ol1 = mfma16(pf1[1].v, ones_b, ol1);
#pragma unroll
    for (int ks = 0; ks < 2; ++ks)
#pragma unroll
      for (int ntc = 0; ntc < 8; ++ntc) {
        int vslot = (ntc * 16 + row16) * 8 + (((ks << 2) + kgrp) ^ (row16 & 7));
        bf16x8 vf = *(const bf16x8*)&vb[vslot * 8];
        o0[ntc] = mfma16(pf0[ks].v, vf, o0[ntc]);
        o1[ntc] = mfma16(pf1[ks].v, vf, o1[ntc]);
      }
  };

  stage(0, 0);
  asm volatile("s_waitcnt vmcnt(0)" ::: "memory");
  __builtin_amdgcn_s_barrier();
  int cur = 0;
  for (int tile = 0; tile < NTILE - 1; ++tile) {
    stage(cur ^ 1, tile + 1);
    compute(cur);
    asm volatile("s_waitcnt vmcnt(0)" ::: "memory");
    __builtin_amdgcn_s_barrier();
    cur ^= 1;
  }
  compute(cur);

  // epilogue: write unnormalized partial O + l (from ones-MFMA, col0 lanes)
  u16* Opw = Op + (size_t)part * (32768 * CCH);
  int tokb = b * NTOK + q0 + w * 32;
#pragma unroll
  for (int r = 0; r < 4; ++r) {
    int tk0 = tokb + kgrp * 4 + r;
    int tk1 = tokb + 16 + kgrp * 4 + r;
#pragma unroll
    for (int ntc = 0; ntc < 8; ++ntc) {
      Opw[(size_t)tk0 * CCH + ntc * 16 + row16] = f2bf(o0[ntc][r]);
      Opw[(size_t)tk1 * CCH + ntc * 16 + row16] = f2bf(o1[ntc][r]);
    }
  }
  if (row16 == 0) {
#pragma unroll
    for (int r = 0; r < 4; ++r) {
      lp[part * 32768 + tokb + kgrp * 4 + r] = ol0[r];
      lp[part * 32768 + tokb + 16 + kgrp * 4 + r] = ol1[r];
    }
  }
}

// ---------------- kernel 3: combine parts + Wo GEMM + bias + residual -------
__global__ __launch_bounds__(256) void out_kernel(
    const u16* __restrict__ Op, const float* __restrict__ lp, int ns,
    const u16* __restrict__ wcomb, const float* __restrict__ bo,
    const float* __restrict__ x, float* __restrict__ out) {
  int t = threadIdx.x;
  int w = t >> 6, lane = t & 63;
  int row16 = lane & 15, kgrp = lane >> 4;
  int tok0 = blockIdx.x * 64;
  int b = tok0 >> 12, tloc = tok0 & (NTOK - 1);
  int tokA = tok0 + w * 16 + row16;
  float lsum = 0.f;
  for (int j = 0; j < ns; ++j) lsum += lp[j * 32768 + tokA];
  float inv = 1.f / lsum;
  bf16x8 af[4];
  for (int ks = 0; ks < 4; ++ks) {
    float sum[8] = {0.f, 0.f, 0.f, 0.f, 0.f, 0.f, 0.f, 0.f};
    for (int j = 0; j < ns; ++j) {
      bf16x8 a = *(const bf16x8*)&Op[(size_t)j * (32768 * CCH) +
                                     (size_t)tokA * CCH + ks * 32 + kgrp * 8];
      for (int e = 0; e < 8; ++e) sum[e] += bf2f((u16)a[e]);
    }
    bf16x8 av;
    for (int e = 0; e < 8; ++e) av[e] = (short)f2bf(sum[e] * inv);
    af[ks] = av;
  }
  f32x4 zero = {0.f, 0.f, 0.f, 0.f};
  f32x4 acc[8];
  for (int nt = 0; nt < 8; ++nt) {
    acc[nt] = zero;
    for (int ks = 0; ks < 4; ++ks) {
      bf16x8 bf = *(const bf16x8*)&wcomb[(size_t)(192 + nt * 16 + row16) * CCH + ks * 32 + kgrp * 8];
      acc[nt] = mfma16(af[ks], bf, acc[nt]);
    }
  }
  for (int nt = 0; nt < 8; ++nt) {
    int cout = nt * 16 + row16;
    float bias = bo[cout];
    size_t base = ((size_t)b * CCH + cout) * NTOK + tloc + w * 16 + kgrp * 4;
    float4 xr = *(const float4*)&x[base];
    float4 ov;
    ov.x = acc[nt][0] + bias + xr.x;
    ov.y = acc[nt][1] + bias + xr.y;
    ov.z = acc[nt][2] + bias + xr.z;
    ov.w = acc[nt][3] + bias + xr.w;
    *(float4*)&out[base] = ov;
  }
}

extern "C" void kernel_launch(void* const* d_in, const int* in_sizes, int n_in,
                              void* d_out, int out_size, void* d_ws, size_t ws_size,
                              hipStream_t stream) {
  const float* x     = (const float*)d_in[0];
  const float* gamma = (const float*)d_in[1];
  const float* beta  = (const float*)d_in[2];
  const float* Wq    = (const float*)d_in[3];
  const float* Wk    = (const float*)d_in[4];
  const float* Wv    = (const float*)d_in[5];
  const float* Wo    = (const float*)d_in[6];
  const float* bo    = (const float*)d_in[7];
  float* out = (float*)d_out;

  unsigned char* ws = (unsigned char*)d_ws;
  u16* Qg    = (u16*)(ws);                  //  2 MB
  u16* Kg    = (u16*)(ws + 2097152);        //  2 MB
  u16* Vt    = (u16*)(ws + 4194304);        //  8 MB [8][128][4096] key-permuted
  u16* wcomb = (u16*)(ws + 12582912);       //  80 KB
  float* lp  = (float*)(ws + 12664832);     //  ns*128 KB
  u16* Op    = (u16*)(ws + 13189120);       //  ns*8 MB

  // split-4 needs 13189120 + 4*8388608 = 46743552 bytes of workspace
  int ns = (ws_size >= 46743552u) ? 4 : 2;

  wconv_kernel<<<160, 256, 0, stream>>>(Wq, Wk, Wv, Wo, wcomb);
  lnqkv_kernel<<<512, 256, 0, stream>>>(x, gamma, beta, wcomb, Qg, Kg, Vt);
  if (ns == 4)
    attn_kernel<4><<<1024, 256, 0, stream>>>(Qg, Kg, Vt, Op, lp);
  else
    attn_kernel<2><<<512, 256, 0, stream>>>(Qg, Kg, Vt, Op, lp);
  out_kernel<<<512, 256, 0, stream>>>(Op, lp, ns, wcomb, bo, x, out);
}